// Round 1
// baseline (203.804 us; speedup 1.0000x reference)
//
#include <hip/hip_runtime.h>
#include <hip/hip_bf16.h>

#define N_ROWS   1024
#define N_FEAT   512
#define HID      256
#define N_KERNEL 10
#define KDIM     10
#define MB_DIM   100
#define CAT      266
#define EPS      1e-3f
#define ALPHA    0.3f

// ---------------------------------------------------------------------------
// Generic tiled fp32 GEMM + bias: C[M,N] = A[M,K] @ W[K,N] + b[N]
// 256 threads as 16x16, each computes TM x TN outputs. BM=16*TM, BN=16*TN.
// ---------------------------------------------------------------------------
template<int BM, int BN, int BK, int TM, int TN>
__global__ __launch_bounds__(256) void gemm_bias_kernel(
    const float* __restrict__ A, const float* __restrict__ W,
    const float* __restrict__ bias, float* __restrict__ C,
    int M, int N, int K)
{
    __shared__ float As[BK][BM + 1];
    __shared__ float Ws[BK][BN + 1];

    const int tx = threadIdx.x & 15;
    const int ty = threadIdx.x >> 4;
    const int row0 = blockIdx.x * BM;
    const int col0 = blockIdx.y * BN;

    float acc[TM][TN];
#pragma unroll
    for (int m = 0; m < TM; ++m)
#pragma unroll
        for (int n = 0; n < TN; ++n) acc[m][n] = 0.f;

    for (int k0 = 0; k0 < K; k0 += BK) {
        // Stage A tile: BM rows x BK cols
        for (int idx = threadIdx.x; idx < BM * BK; idx += 256) {
            int r  = idx / BK;
            int kk = idx % BK;
            int gk = k0 + kk;
            As[kk][r] = (gk < K) ? A[(row0 + r) * K + gk] : 0.f;
        }
        // Stage W tile: BK rows x BN cols
        for (int idx = threadIdx.x; idx < BK * BN; idx += 256) {
            int kk = idx / BN;
            int c  = idx % BN;
            int gk = k0 + kk;
            int gc = col0 + c;
            Ws[kk][c] = (gk < K && gc < N) ? W[gk * N + gc] : 0.f;
        }
        __syncthreads();

#pragma unroll
        for (int kk = 0; kk < BK; ++kk) {
            float a[TM], w[TN];
#pragma unroll
            for (int m = 0; m < TM; ++m) a[m] = As[kk][ty * TM + m];
#pragma unroll
            for (int n = 0; n < TN; ++n) w[n] = Ws[kk][tx * TN + n];
#pragma unroll
            for (int m = 0; m < TM; ++m)
#pragma unroll
                for (int n = 0; n < TN; ++n) acc[m][n] += a[m] * w[n];
        }
        __syncthreads();
    }

#pragma unroll
    for (int m = 0; m < TM; ++m) {
        int r = row0 + ty * TM + m;
#pragma unroll
        for (int n = 0; n < TN; ++n) {
            int c = col0 + tx * TN + n;
            if (c < N) C[r * N + c] = acc[m][n] + bias[c];
        }
    }
}

// ---------------------------------------------------------------------------
// Batch diversity: div[i][k] = sum_j exp(-sum_d |M[i,k*10+d] - M[j,k*10+d]|)
// grid (16, 10), block 256. LDS holds the full [1024 x 10] slice for kernel k.
// Each thread: one row i (t&63 within 64-row tile) and one j-chunk (t>>6).
// Inner j-loop is wave-uniform -> LDS broadcast reads, no bank conflicts.
// ---------------------------------------------------------------------------
__global__ __launch_bounds__(256) void diversity_kernel(
    const float* __restrict__ M, float* __restrict__ divOut)
{
    __shared__ float Ms[N_ROWS * KDIM];   // 40 KB
    __shared__ float red[256];

    const int k = blockIdx.y;

    for (int idx = threadIdx.x; idx < N_ROWS * KDIM; idx += 256) {
        int j = idx / KDIM;
        int d = idx - j * KDIM;
        Ms[idx] = M[j * MB_DIM + k * KDIM + d];
    }
    __syncthreads();

    const int t  = threadIdx.x;
    const int i  = blockIdx.x * 64 + (t & 63);
    const int jc = t >> 6;   // 0..3

    float Mi[KDIM];
#pragma unroll
    for (int d = 0; d < KDIM; ++d) Mi[d] = Ms[i * KDIM + d];

    float acc = 0.f;
    const int jBeg = jc * (N_ROWS / 4);
    const int jEnd = jBeg + (N_ROWS / 4);
    for (int j = jBeg; j < jEnd; ++j) {
        float l1 = 0.f;
#pragma unroll
        for (int d = 0; d < KDIM; ++d) l1 += fabsf(Mi[d] - Ms[j * KDIM + d]);
        acc += __expf(-l1);
    }

    red[t] = acc;
    __syncthreads();
    if (t < 64) {
        float s = red[t] + red[t + 64] + red[t + 128] + red[t + 192];
        divOut[i * N_KERNEL + k] = s;
    }
}

// ---------------------------------------------------------------------------
// Fused center-only LayerNorm + beta + LeakyReLU over concat([h, div], dim=1).
// One block (256 thr) per row. h: [1024,256], div: [1024,10], out: [1024,266].
// ---------------------------------------------------------------------------
__global__ __launch_bounds__(256) void ln_lrelu_kernel(
    const float* __restrict__ h, const float* __restrict__ divIn,
    const float* __restrict__ beta, float* __restrict__ out)
{
    const int row = blockIdx.x;
    const int t = threadIdx.x;

    float v1 = h[row * HID + t];
    float v2 = (t < N_KERNEL) ? divIn[row * N_KERNEL + t] : 0.f;

    float s  = v1 + v2;
    float sq = v1 * v1 + v2 * v2;

    __shared__ float rs[4], rq[4];
#pragma unroll
    for (int off = 32; off > 0; off >>= 1) {
        s  += __shfl_down(s, off);
        sq += __shfl_down(sq, off);
    }
    const int lane = t & 63, w = t >> 6;
    if (lane == 0) { rs[w] = s; rq[w] = sq; }
    __syncthreads();

    const float tot  = rs[0] + rs[1] + rs[2] + rs[3];
    const float totq = rq[0] + rq[1] + rq[2] + rq[3];
    const float mean = tot * (1.f / (float)CAT);
    const float var  = totq * (1.f / (float)CAT) - mean * mean;
    const float inv  = rsqrtf(var + EPS);

    float x1 = (v1 - mean) * inv + beta[t];
    out[row * CAT + t] = (x1 > 0.f) ? x1 : ALPHA * x1;
    if (t < N_KERNEL) {
        float x2 = (v2 - mean) * inv + beta[HID + t];
        out[row * CAT + HID + t] = (x2 > 0.f) ? x2 : ALPHA * x2;
    }
}

// ---------------------------------------------------------------------------
// Final head: out[i] = dot(a1[i, 0:266], Wf) + bf. One wave per row.
// ---------------------------------------------------------------------------
__global__ __launch_bounds__(256) void final_dot_kernel(
    const float* __restrict__ A, const float* __restrict__ Wf,
    const float* __restrict__ bf, float* __restrict__ out)
{
    const int wave = threadIdx.x >> 6;
    const int lane = threadIdx.x & 63;
    const int row  = blockIdx.x * 4 + wave;

    const float* a = A + row * CAT;
    float s = 0.f;
    for (int c = lane; c < CAT; c += 64) s += a[c] * Wf[c];
#pragma unroll
    for (int off = 32; off > 0; off >>= 1) s += __shfl_down(s, off);
    if (lane == 0) out[row] = s + bf[0];
}

// ---------------------------------------------------------------------------
extern "C" void kernel_launch(void* const* d_in, const int* in_sizes, int n_in,
                              void* d_out, int out_size, void* d_ws, size_t ws_size,
                              hipStream_t stream)
{
    const float* x     = (const float*)d_in[0];
    const float* W0    = (const float*)d_in[1];
    const float* b0    = (const float*)d_in[2];
    const float* Wd0   = (const float*)d_in[3];
    const float* bd0   = (const float*)d_in[4];
    const float* beta0 = (const float*)d_in[5];
    const float* W1    = (const float*)d_in[6];
    const float* b1    = (const float*)d_in[7];
    const float* Wd1   = (const float*)d_in[8];
    const float* bd1   = (const float*)d_in[9];
    const float* beta1 = (const float*)d_in[10];
    const float* Wf    = (const float*)d_in[11];
    const float* bf    = (const float*)d_in[12];
    float* out = (float*)d_out;

    float* ws = (float*)d_ws;
    float* h0   = ws;                        // 1024*256
    float* M0   = h0   + N_ROWS * HID;       // 1024*100
    float* div0 = M0   + N_ROWS * MB_DIM;    // 1024*10
    float* a0   = div0 + N_ROWS * N_KERNEL;  // 1024*266
    float* h1   = a0   + N_ROWS * CAT;       // 1024*256
    float* M1   = h1   + N_ROWS * HID;       // 1024*100
    float* div1 = M1   + N_ROWS * MB_DIM;    // 1024*10
    float* a1   = div1 + N_ROWS * N_KERNEL;  // 1024*266

    dim3 blk(256);

    // Block 0
    gemm_bias_kernel<64, 32, 16, 4, 2><<<dim3(16, 8), blk, 0, stream>>>(
        x, W0, b0, h0, N_ROWS, HID, N_FEAT);
    gemm_bias_kernel<64, 32, 16, 4, 2><<<dim3(16, 4), blk, 0, stream>>>(
        h0, Wd0, bd0, M0, N_ROWS, MB_DIM, HID);
    diversity_kernel<<<dim3(16, N_KERNEL), blk, 0, stream>>>(M0, div0);
    ln_lrelu_kernel<<<dim3(N_ROWS), blk, 0, stream>>>(h0, div0, beta0, a0);

    // Block 1
    gemm_bias_kernel<64, 32, 16, 4, 2><<<dim3(16, 8), blk, 0, stream>>>(
        a0, W1, b1, h1, N_ROWS, HID, CAT);
    gemm_bias_kernel<64, 32, 16, 4, 2><<<dim3(16, 4), blk, 0, stream>>>(
        h1, Wd1, bd1, M1, N_ROWS, MB_DIM, HID);
    diversity_kernel<<<dim3(16, N_KERNEL), blk, 0, stream>>>(M1, div1);
    ln_lrelu_kernel<<<dim3(N_ROWS), blk, 0, stream>>>(h1, div1, beta1, a1);

    // Head
    final_dot_kernel<<<dim3(N_ROWS / 4), blk, 0, stream>>>(a1, Wf, bf, out);
}

// Round 2
// 94.987 us; speedup vs baseline: 2.1456x; 2.1456x over previous
//
#include <hip/hip_runtime.h>
#include <hip/hip_bf16.h>

#define N_ROWS   1024
#define N_FEAT   512
#define HID      256
#define N_KERNEL 10
#define KDIM     10
#define MB_DIM   100
#define CAT      266
#define KPAD     288      // a0 padded K (multiple of 32, 16B-aligned rows)
#define EPS      1e-3f
#define ALPHA    0.3f

// ---------------------------------------------------------------------------
// Tiled fp32 GEMM + bias, register->LDS double-buffered.
// C[M,N] = A[M,K(sA stride)] @ W[0:Kw, N] + bias  (A cols >= Kw are zeros)
// 256 threads. BK=32, BN=32 fixed. Grid (M/BM, ceil(N/32)).
// ---------------------------------------------------------------------------
template<int BM, int BN, int BK, int TM, int TN, bool GN>
__global__ __launch_bounds__(256) void gemm_bias(
    const float* __restrict__ A, const float* __restrict__ W,
    const float* __restrict__ bias, float* __restrict__ C,
    int M, int N, int K, int Kw, int sA)
{
    static_assert(BK == 32 && BN == 32, "fixed staging geometry");
    constexpr int TX = BN / TN;
    constexpr int TY = BM / TM;
    static_assert(TX * TY == 256, "256 threads");
    constexpr int VA = (BM * BK) / 256;   // floats per thread for A stage
    static_assert(VA == 2 || VA == 4, "VA");

    __shared__ float As[2][BK][BM + 2];
    __shared__ float Ws[2][BK][BN];

    const int t  = threadIdx.x;
    const int tx = t % TX;
    const int ty = t / TX;
    const int row0 = blockIdx.x * BM;
    const int col0 = blockIdx.y * BN;

    float aR[VA];
    float4 wR;

    auto loadT = [&](int k0) {
        if constexpr (VA == 4) {
            const int r = t >> 3, kv = t & 7;
            const float4 v = *(const float4*)&A[(size_t)(row0 + r) * sA + k0 + kv * 4];
            aR[0] = v.x; aR[1] = v.y; aR[2] = v.z; aR[3] = v.w;
        } else {
            const int r = t >> 4, kv = t & 15;
            const float2 v = *(const float2*)&A[(size_t)(row0 + r) * sA + k0 + kv * 2];
            aR[0] = v.x; aR[1] = v.y;
        }
        const int kk = t >> 3, cv = t & 7;
        const int gk = k0 + kk, gc = col0 + cv * 4;
        float4 wv = make_float4(0.f, 0.f, 0.f, 0.f);
        if (gk < Kw) {
            if (!GN || gc + 3 < N) {
                wv = *(const float4*)&W[(size_t)gk * N + gc];
            } else {
                float tmp[4] = {0.f, 0.f, 0.f, 0.f};
#pragma unroll
                for (int i = 0; i < 4; ++i)
                    if (gc + i < N) tmp[i] = W[(size_t)gk * N + gc + i];
                wv = make_float4(tmp[0], tmp[1], tmp[2], tmp[3]);
            }
        }
        wR = wv;
    };
    auto storeT = [&](int b) {
        if constexpr (VA == 4) {
            const int r = t >> 3, kv = t & 7;
#pragma unroll
            for (int i = 0; i < 4; ++i) As[b][kv * 4 + i][r] = aR[i];
        } else {
            const int r = t >> 4, kv = t & 15;
            As[b][kv * 2 + 0][r] = aR[0];
            As[b][kv * 2 + 1][r] = aR[1];
        }
        const int kk = t >> 3, cv = t & 7;
        *(float4*)&Ws[b][kk][cv * 4] = wR;
    };

    loadT(0);
    storeT(0);
    __syncthreads();

    float acc[TM][TN];
#pragma unroll
    for (int m = 0; m < TM; ++m)
#pragma unroll
        for (int n = 0; n < TN; ++n) acc[m][n] = 0.f;

    const int nT = K / BK;
    for (int ti = 0; ti < nT; ++ti) {
        const int cur = ti & 1;
        if (ti + 1 < nT) loadT((ti + 1) * BK);

#pragma unroll
        for (int kk = 0; kk < BK; ++kk) {
            float a[TM], w[TN];
            if constexpr (TM == 2) {
                const float2 v = *(const float2*)&As[cur][kk][ty * 2];
                a[0] = v.x; a[1] = v.y;
            } else {
                a[0] = As[cur][kk][ty];
            }
            if constexpr (TN == 4) {
                const float4 v = *(const float4*)&Ws[cur][kk][tx * 4];
                w[0] = v.x; w[1] = v.y; w[2] = v.z; w[3] = v.w;
            } else {
                const float2 v = *(const float2*)&Ws[cur][kk][tx * 2];
                w[0] = v.x; w[1] = v.y;
            }
#pragma unroll
            for (int m = 0; m < TM; ++m)
#pragma unroll
                for (int n = 0; n < TN; ++n) acc[m][n] += a[m] * w[n];
        }
        if (ti + 1 < nT) {
            __syncthreads();
            storeT(1 - cur);
            __syncthreads();
        }
    }

#pragma unroll
    for (int m = 0; m < TM; ++m) {
        const int r = row0 + ty * TM + m;
#pragma unroll
        for (int n = 0; n < TN; ++n) {
            const int c = col0 + tx * TN + n;
            if (!GN || c < N) C[(size_t)r * N + c] = acc[m][n] + bias[c];
        }
    }
}

// ---------------------------------------------------------------------------
// Batch diversity: div[i][k] = sum_j exp(-sum_d |M[i,kd]-M[j,kd]|)
// grid (32, 10), 256 thr: 32 rows x 8 j-chunks(128 each). M slice staged as
// [1024][12] (float4-aligned rows). Vectorized b128/b64 LDS reads.
// ---------------------------------------------------------------------------
__global__ __launch_bounds__(256) void diversity_kernel(
    const float* __restrict__ M, float* __restrict__ divOut)
{
    __shared__ float Ms[N_ROWS * 12];   // 48 KB
    __shared__ float red[256];

    const int k = blockIdx.y;
    const int t = threadIdx.x;

    for (int idx = t; idx < N_ROWS * 5; idx += 256) {
        const int j = idx / 5;
        const int dd = idx - j * 5;
        const float2 v = *(const float2*)&M[(size_t)j * MB_DIM + k * KDIM + dd * 2];
        Ms[j * 12 + dd * 2 + 0] = v.x;
        Ms[j * 12 + dd * 2 + 1] = v.y;
    }
    __syncthreads();

    const int il = t & 31;            // row within tile
    const int jc = t >> 5;            // 0..7 j-chunk
    const int i  = blockIdx.x * 32 + il;

    float Mi[KDIM];
#pragma unroll
    for (int d = 0; d < KDIM; ++d) Mi[d] = Ms[i * 12 + d];

    float acc = 0.f;
    const int jBeg = jc * 128;
#pragma unroll 2
    for (int j = jBeg; j < jBeg + 128; ++j) {
        const float4 v0 = *(const float4*)&Ms[j * 12];
        const float4 v1 = *(const float4*)&Ms[j * 12 + 4];
        const float2 v2 = *(const float2*)&Ms[j * 12 + 8];
        float l1 = fabsf(Mi[0] - v0.x) + fabsf(Mi[1] - v0.y)
                 + fabsf(Mi[2] - v0.z) + fabsf(Mi[3] - v0.w)
                 + fabsf(Mi[4] - v1.x) + fabsf(Mi[5] - v1.y)
                 + fabsf(Mi[6] - v1.z) + fabsf(Mi[7] - v1.w)
                 + fabsf(Mi[8] - v2.x) + fabsf(Mi[9] - v2.y);
        acc += __expf(-l1);
    }

    red[t] = acc;
    __syncthreads();
    if (t < 32) {
        float s = 0.f;
#pragma unroll
        for (int c = 0; c < 8; ++c) s += red[c * 32 + t];
        divOut[(size_t)(blockIdx.x * 32 + t) * N_KERNEL + k] = s;
    }
}

// ---------------------------------------------------------------------------
// Center-only LN + beta + LeakyReLU. Writes a0 padded to stride KPAD(288),
// zeroing cols 266..287 so GEMM1 can run a clean K=288 with aligned float4s.
// ---------------------------------------------------------------------------
__global__ __launch_bounds__(256) void ln_lrelu_pad(
    const float* __restrict__ h, const float* __restrict__ divIn,
    const float* __restrict__ beta, float* __restrict__ out)
{
    const int row = blockIdx.x;
    const int t = threadIdx.x;

    const float v1 = h[(size_t)row * HID + t];
    const float v2 = (t < N_KERNEL) ? divIn[(size_t)row * N_KERNEL + t] : 0.f;

    float s  = v1 + v2;
    float sq = v1 * v1 + v2 * v2;

    __shared__ float rs[4], rq[4];
#pragma unroll
    for (int off = 32; off > 0; off >>= 1) {
        s  += __shfl_down(s, off);
        sq += __shfl_down(sq, off);
    }
    const int lane = t & 63, w = t >> 6;
    if (lane == 0) { rs[w] = s; rq[w] = sq; }
    __syncthreads();

    const float tot  = rs[0] + rs[1] + rs[2] + rs[3];
    const float totq = rq[0] + rq[1] + rq[2] + rq[3];
    const float mean = tot * (1.f / (float)CAT);
    const float var  = totq * (1.f / (float)CAT) - mean * mean;
    const float inv  = rsqrtf(var + EPS);

    float x1 = (v1 - mean) * inv + beta[t];
    out[(size_t)row * KPAD + t] = (x1 > 0.f) ? x1 : ALPHA * x1;
    if (t < N_KERNEL) {
        float x2 = (v2 - mean) * inv + beta[HID + t];
        out[(size_t)row * KPAD + HID + t] = (x2 > 0.f) ? x2 : ALPHA * x2;
    }
    if (t < KPAD - CAT) out[(size_t)row * KPAD + CAT + t] = 0.f;
}

// ---------------------------------------------------------------------------
// LN + LeakyReLU + final dot with Wf (fused head). One block per row.
// ---------------------------------------------------------------------------
__global__ __launch_bounds__(256) void ln_final(
    const float* __restrict__ h, const float* __restrict__ divIn,
    const float* __restrict__ beta, const float* __restrict__ Wf,
    const float* __restrict__ bf, float* __restrict__ out)
{
    const int row = blockIdx.x;
    const int t = threadIdx.x;

    const float v1 = h[(size_t)row * HID + t];
    const float v2 = (t < N_KERNEL) ? divIn[(size_t)row * N_KERNEL + t] : 0.f;

    float s  = v1 + v2;
    float sq = v1 * v1 + v2 * v2;

    __shared__ float rs[4], rq[4], rd[4];
#pragma unroll
    for (int off = 32; off > 0; off >>= 1) {
        s  += __shfl_down(s, off);
        sq += __shfl_down(sq, off);
    }
    const int lane = t & 63, w = t >> 6;
    if (lane == 0) { rs[w] = s; rq[w] = sq; }
    __syncthreads();

    const float tot  = rs[0] + rs[1] + rs[2] + rs[3];
    const float totq = rq[0] + rq[1] + rq[2] + rq[3];
    const float mean = tot * (1.f / (float)CAT);
    const float var  = totq * (1.f / (float)CAT) - mean * mean;
    const float inv  = rsqrtf(var + EPS);

    float x1 = (v1 - mean) * inv + beta[t];
    x1 = (x1 > 0.f) ? x1 : ALPHA * x1;
    float d = x1 * Wf[t];
    if (t < N_KERNEL) {
        float x2 = (v2 - mean) * inv + beta[HID + t];
        x2 = (x2 > 0.f) ? x2 : ALPHA * x2;
        d += x2 * Wf[HID + t];
    }
#pragma unroll
    for (int off = 32; off > 0; off >>= 1) d += __shfl_down(d, off);
    if (lane == 0) rd[w] = d;
    __syncthreads();
    if (t == 0) out[row] = rd[0] + rd[1] + rd[2] + rd[3] + bf[0];
}

// ---------------------------------------------------------------------------
extern "C" void kernel_launch(void* const* d_in, const int* in_sizes, int n_in,
                              void* d_out, int out_size, void* d_ws, size_t ws_size,
                              hipStream_t stream)
{
    const float* x     = (const float*)d_in[0];
    const float* W0    = (const float*)d_in[1];
    const float* b0    = (const float*)d_in[2];
    const float* Wd0   = (const float*)d_in[3];
    const float* bd0   = (const float*)d_in[4];
    const float* beta0 = (const float*)d_in[5];
    const float* W1    = (const float*)d_in[6];
    const float* b1    = (const float*)d_in[7];
    const float* Wd1   = (const float*)d_in[8];
    const float* bd1   = (const float*)d_in[9];
    const float* beta1 = (const float*)d_in[10];
    const float* Wf    = (const float*)d_in[11];
    const float* bf    = (const float*)d_in[12];
    float* out = (float*)d_out;

    float* ws = (float*)d_ws;
    float* h0   = ws;                          // 1024*256
    float* M0   = h0   + N_ROWS * HID;         // 1024*100
    float* div0 = M0   + N_ROWS * MB_DIM;      // 1024*10
    float* a0p  = div0 + N_ROWS * N_KERNEL;    // 1024*288
    float* h1   = a0p  + N_ROWS * KPAD;        // 1024*256
    float* M1   = h1   + N_ROWS * HID;         // 1024*100
    float* div1 = M1   + N_ROWS * MB_DIM;      // 1024*10

    dim3 blk(256);

    // --- block 0 ---
    gemm_bias<32, 32, 32, 2, 2, false><<<dim3(32, 8), blk, 0, stream>>>(
        x, W0, b0, h0, N_ROWS, HID, N_FEAT, N_FEAT, N_FEAT);
    gemm_bias<16, 32, 32, 1, 2, true><<<dim3(64, 4), blk, 0, stream>>>(
        h0, Wd0, bd0, M0, N_ROWS, MB_DIM, HID, HID, HID);
    diversity_kernel<<<dim3(32, N_KERNEL), blk, 0, stream>>>(M0, div0);
    ln_lrelu_pad<<<dim3(N_ROWS), blk, 0, stream>>>(h0, div0, beta0, a0p);

    // --- block 1 ---
    gemm_bias<32, 32, 32, 2, 2, false><<<dim3(32, 8), blk, 0, stream>>>(
        a0p, W1, b1, h1, N_ROWS, HID, KPAD, CAT, KPAD);
    gemm_bias<16, 32, 32, 1, 2, true><<<dim3(64, 4), blk, 0, stream>>>(
        h1, Wd1, bd1, M1, N_ROWS, MB_DIM, HID, HID, HID);
    diversity_kernel<<<dim3(32, N_KERNEL), blk, 0, stream>>>(M1, div1);

    // --- fused LN + head ---
    ln_final<<<dim3(N_ROWS), blk, 0, stream>>>(h1, div1, beta1, Wf, bf, out);
}

// Round 3
// 77.908 us; speedup vs baseline: 2.6160x; 1.2192x over previous
//
#include <hip/hip_runtime.h>

typedef __attribute__((ext_vector_type(8))) short short8;
typedef __attribute__((ext_vector_type(4))) float f32x4;

#define N_ROWS   1024
#define N_FEAT   512
#define HID      256
#define N_KERNEL 10
#define KDIM     10
#define MB       128     // padded M-matrix width (real 100)
#define CAT      266
#define KPAD     288     // padded concat width (multiple of 32)
#define EPS      1e-3f
#define ALPHA    0.3f

// fp32 -> bf16 round-to-nearest-even (bit-level, no header-type dependency)
__device__ __forceinline__ unsigned short f2bf(float f) {
    unsigned u = __float_as_uint(f);
    unsigned r = u + 0x7FFFu + ((u >> 16) & 1u);
    return (unsigned short)(r >> 16);
}

// ---------------------------------------------------------------------------
// Convert + transpose + pad all bf16 operands, and compute bcomb = b@Wd + bd.
// Layouts produced (all bf16 = ushort):
//   xb    [1024][512]            straight
//   W0b   [512][256]             straight (B'^T for the Wc0 GEMM)
//   W0bT  [256][512]             transposed (B^T for h0 GEMM)
//   Wd0bT [128][256]             transposed, cols>=100 zero (A' for Wc0 GEMM)
//   W1b   [288][256]             straight, rows>=266 zero
//   W1bT  [256][288]             transposed, k>=266 zero
//   Wd1bT [128][256]             transposed, padded
// ---------------------------------------------------------------------------
__global__ __launch_bounds__(256) void conv_kernel(
    const float* __restrict__ x,
    const float* __restrict__ W0, const float* __restrict__ Wd0,
    const float* __restrict__ W1, const float* __restrict__ Wd1,
    const float* __restrict__ b0, const float* __restrict__ bd0,
    const float* __restrict__ b1, const float* __restrict__ bd1,
    unsigned short* __restrict__ xb,
    unsigned short* __restrict__ W0b, unsigned short* __restrict__ W0bT,
    unsigned short* __restrict__ Wd0bT,
    unsigned short* __restrict__ W1b, unsigned short* __restrict__ W1bT,
    unsigned short* __restrict__ Wd1bT,
    float* __restrict__ bcomb0, float* __restrict__ bcomb1)
{
    const int bx = blockIdx.x;
    if (bx >= 512) {                        // bcomb blocks
        const float* b  = (bx == 512) ? b0  : b1;
        const float* Wd = (bx == 512) ? Wd0 : Wd1;
        const float* bd = (bx == 512) ? bd0 : bd1;
        float* o        = (bx == 512) ? bcomb0 : bcomb1;
        const int c = threadIdx.x;
        if (c < MB) {
            float s = 0.f;
            if (c < 100) {
                s = bd[c];
                for (int k = 0; k < HID; ++k) s += b[k] * Wd[k * 100 + c];
            }
            o[c] = s;
        }
        return;
    }
    const int S0 = 1024 * 512;
    const int S1 = S0 + 512 * 256;
    const int S2 = S1 + 256 * 512;
    const int S3 = S2 + 128 * 256;
    const int S4 = S3 + 288 * 256;
    const int S5 = S4 + 256 * 288;
    const int S6 = S5 + 128 * 256;
    for (int o = bx * 256 + threadIdx.x; o < S6; o += 512 * 256) {
        if (o < S0) {
            xb[o] = f2bf(x[o]);
        } else if (o < S1) {
            const int i = o - S0;
            W0b[i] = f2bf(W0[i]);
        } else if (o < S2) {
            const int i = o - S1, n = i >> 9, k = i & 511;
            W0bT[i] = f2bf(W0[k * 256 + n]);
        } else if (o < S3) {
            const int i = o - S2, c = i >> 8, k = i & 255;
            Wd0bT[i] = (c < 100) ? f2bf(Wd0[k * 100 + c]) : (unsigned short)0;
        } else if (o < S4) {
            const int i = o - S3, r = i >> 8;
            W1b[i] = (r < CAT) ? f2bf(W1[i]) : (unsigned short)0;
        } else if (o < S5) {
            const int i = o - S4, n = i / KPAD, kk = i - n * KPAD;
            W1bT[i] = (kk < CAT) ? f2bf(W1[kk * 256 + n]) : (unsigned short)0;
        } else {
            const int i = o - S5, c = i >> 8, k = i & 255;
            Wd1bT[i] = (c < 100) ? f2bf(Wd1[k * 100 + c]) : (unsigned short)0;
        }
    }
}

// ---------------------------------------------------------------------------
// WcT = (W @ Wd)^T via MFMA: C'[c][n] = sum_k Wd^T[c][k] * W[n][k].
// A' = WdbT [128][256], B'^T = Wb [N'][256], C' = WcbT [128][N'] (bf16 out).
// bx<64: Wc0 (N'=512) ; bx>=64: Wc1 (N'=288). 32x32 tile per block, 4 waves.
// ---------------------------------------------------------------------------
__global__ __launch_bounds__(256) void wc_mfma(
    const unsigned short* __restrict__ Wd0bT, const unsigned short* __restrict__ W0b,
    unsigned short* __restrict__ Wc0bT,
    const unsigned short* __restrict__ Wd1bT, const unsigned short* __restrict__ W1b,
    unsigned short* __restrict__ Wc1bT)
{
    const int bx = blockIdx.x;
    const unsigned short *Ab, *Bb;
    unsigned short* Cb;
    int NN, mt, nt;
    if (bx < 64) { Ab = Wd0bT; Bb = W0b; Cb = Wc0bT; NN = 512;  mt = bx & 3; nt = bx >> 2; }
    else { const int s = bx - 64; Ab = Wd1bT; Bb = W1b; Cb = Wc1bT; NN = KPAD; mt = s & 3; nt = s >> 2; }

    const int t = threadIdx.x, lane = t & 63, w = t >> 6;
    const int wr = w >> 1, wn = w & 1, r = lane & 15, g = lane >> 4;
    const int arow = mt * 32 + wr * 16 + r;
    const int bcol = nt * 32 + wn * 16 + r;
    const unsigned short* Ap = Ab + (size_t)arow * 256 + g * 8;
    const unsigned short* Bp = Bb + (size_t)bcol * 256 + g * 8;

    f32x4 acc = {0.f, 0.f, 0.f, 0.f};
#pragma unroll
    for (int k0 = 0; k0 < 256; k0 += 32) {
        short8 a = *(const short8*)(Ap + k0);
        short8 b = *(const short8*)(Bp + k0);
        acc = __builtin_amdgcn_mfma_f32_16x16x32_bf16(a, b, acc, 0, 0, 0);
    }
    const int orow0 = mt * 32 + wr * 16 + g * 4;
    const int ocol  = nt * 32 + wn * 16 + r;
#pragma unroll
    for (int i = 0; i < 4; ++i)
        Cb[(size_t)(orow0 + i) * NN + ocol] = f2bf(acc[i]);
}

// ---------------------------------------------------------------------------
// Fused h-GEMM + M-GEMM (both read the same A):
//   by<8 : Ch[1024][256] = A @ BTh^T + biash   (h = x@W + b)
//   by>=8: Cm[1024][128] = A @ BTm^T + biasm   (M = x@Wc + bcomb)
// One 16x16 C-tile per wave, no LDS, fragments straight from L2.
// ---------------------------------------------------------------------------
__global__ __launch_bounds__(256) void hm_mfma(
    const unsigned short* __restrict__ A, int ldk,
    const unsigned short* __restrict__ BTh, const float* __restrict__ biash,
    float* __restrict__ Ch,
    const unsigned short* __restrict__ BTm, const float* __restrict__ biasm,
    float* __restrict__ Cm)
{
    const int t = threadIdx.x, lane = t & 63, w = t >> 6;
    const int wr = w >> 1, wn = w & 1, r = lane & 15, g = lane >> 4;
    const bool isM = blockIdx.y >= 8;
    const int colBase = (isM ? (int)blockIdx.y - 8 : (int)blockIdx.y) * 32 + wn * 16;
    const unsigned short* BT = isM ? BTm : BTh;
    const float* bias = isM ? biasm : biash;
    float* C = isM ? Cm : Ch;
    const int ldc = isM ? MB : HID;

    const int arow = blockIdx.x * 32 + wr * 16 + r;
    const int bcol = colBase + r;
    const unsigned short* Ap = A + (size_t)arow * ldk + g * 8;
    const unsigned short* Bp = BT + (size_t)bcol * ldk + g * 8;

    f32x4 acc = {0.f, 0.f, 0.f, 0.f};
#pragma unroll 4
    for (int k0 = 0; k0 < ldk; k0 += 32) {
        short8 a = *(const short8*)(Ap + k0);
        short8 b = *(const short8*)(Bp + k0);
        acc = __builtin_amdgcn_mfma_f32_16x16x32_bf16(a, b, acc, 0, 0, 0);
    }
    const float bv = bias[bcol];
    const int orow0 = blockIdx.x * 32 + wr * 16 + g * 4;
#pragma unroll
    for (int i = 0; i < 4; ++i)
        C[(size_t)(orow0 + i) * ldc + bcol] = acc[i] + bv;
}

// ---------------------------------------------------------------------------
// Batch diversity on M [1024][128] fp32 (cols 0..99 live).
// grid (32,10), 256 thr: 32 rows x 8 j-chunks. LDS slice [1024][12].
// ---------------------------------------------------------------------------
__global__ __launch_bounds__(256) void diversity_kernel(
    const float* __restrict__ M, float* __restrict__ divOut)
{
    __shared__ float Ms[N_ROWS * 12];
    __shared__ float red[256];

    const int k = blockIdx.y;
    const int t = threadIdx.x;

    for (int idx = t; idx < N_ROWS * 5; idx += 256) {
        const int j = idx / 5;
        const int dd = idx - j * 5;
        const float2 v = *(const float2*)&M[(size_t)j * MB + k * KDIM + dd * 2];
        Ms[j * 12 + dd * 2 + 0] = v.x;
        Ms[j * 12 + dd * 2 + 1] = v.y;
    }
    __syncthreads();

    const int il = t & 31;
    const int jc = t >> 5;
    const int i  = blockIdx.x * 32 + il;

    float Mi[KDIM];
#pragma unroll
    for (int d = 0; d < KDIM; ++d) Mi[d] = Ms[i * 12 + d];

    float acc = 0.f;
    const int jBeg = jc * 128;
#pragma unroll 2
    for (int j = jBeg; j < jBeg + 128; ++j) {
        const float4 v0 = *(const float4*)&Ms[j * 12];
        const float4 v1 = *(const float4*)&Ms[j * 12 + 4];
        const float2 v2 = *(const float2*)&Ms[j * 12 + 8];
        float l1 = fabsf(Mi[0] - v0.x) + fabsf(Mi[1] - v0.y)
                 + fabsf(Mi[2] - v0.z) + fabsf(Mi[3] - v0.w)
                 + fabsf(Mi[4] - v1.x) + fabsf(Mi[5] - v1.y)
                 + fabsf(Mi[6] - v1.z) + fabsf(Mi[7] - v1.w)
                 + fabsf(Mi[8] - v2.x) + fabsf(Mi[9] - v2.y);
        acc += __expf(-l1);
    }

    red[t] = acc;
    __syncthreads();
    if (t < 32) {
        float s = 0.f;
#pragma unroll
        for (int c = 0; c < 8; ++c) s += red[c * 32 + t];
        divOut[(size_t)(blockIdx.x * 32 + t) * N_KERNEL + k] = s;
    }
}

// ---------------------------------------------------------------------------
// Center-only LN + beta + LeakyReLU -> bf16 a0 padded to [1024][288].
// ---------------------------------------------------------------------------
__global__ __launch_bounds__(256) void ln_bf16_pad(
    const float* __restrict__ h, const float* __restrict__ divIn,
    const float* __restrict__ beta, unsigned short* __restrict__ outb)
{
    const int row = blockIdx.x;
    const int t = threadIdx.x;

    const float v1 = h[(size_t)row * HID + t];
    const float v2 = (t < N_KERNEL) ? divIn[(size_t)row * N_KERNEL + t] : 0.f;

    float s  = v1 + v2;
    float sq = v1 * v1 + v2 * v2;

    __shared__ float rs[4], rq[4];
#pragma unroll
    for (int off = 32; off > 0; off >>= 1) {
        s  += __shfl_down(s, off);
        sq += __shfl_down(sq, off);
    }
    const int lane = t & 63, w = t >> 6;
    if (lane == 0) { rs[w] = s; rq[w] = sq; }
    __syncthreads();

    const float tot  = rs[0] + rs[1] + rs[2] + rs[3];
    const float totq = rq[0] + rq[1] + rq[2] + rq[3];
    const float mean = tot * (1.f / (float)CAT);
    const float var  = totq * (1.f / (float)CAT) - mean * mean;
    const float inv  = rsqrtf(var + EPS);

    float x1 = (v1 - mean) * inv + beta[t];
    x1 = (x1 > 0.f) ? x1 : ALPHA * x1;
    outb[(size_t)row * KPAD + t] = f2bf(x1);
    if (t < N_KERNEL) {
        float x2 = (v2 - mean) * inv + beta[HID + t];
        x2 = (x2 > 0.f) ? x2 : ALPHA * x2;
        outb[(size_t)row * KPAD + HID + t] = f2bf(x2);
    }
    if (t < KPAD - CAT) outb[(size_t)row * KPAD + CAT + t] = 0;
}

// ---------------------------------------------------------------------------
// LN + LeakyReLU + final dot with Wf (fp32). One block per row.
// ---------------------------------------------------------------------------
__global__ __launch_bounds__(256) void ln_final(
    const float* __restrict__ h, const float* __restrict__ divIn,
    const float* __restrict__ beta, const float* __restrict__ Wf,
    const float* __restrict__ bf, float* __restrict__ out)
{
    const int row = blockIdx.x;
    const int t = threadIdx.x;

    const float v1 = h[(size_t)row * HID + t];
    const float v2 = (t < N_KERNEL) ? divIn[(size_t)row * N_KERNEL + t] : 0.f;

    float s  = v1 + v2;
    float sq = v1 * v1 + v2 * v2;

    __shared__ float rs[4], rq[4], rd[4];
#pragma unroll
    for (int off = 32; off > 0; off >>= 1) {
        s  += __shfl_down(s, off);
        sq += __shfl_down(sq, off);
    }
    const int lane = t & 63, w = t >> 6;
    if (lane == 0) { rs[w] = s; rq[w] = sq; }
    __syncthreads();

    const float tot  = rs[0] + rs[1] + rs[2] + rs[3];
    const float totq = rq[0] + rq[1] + rq[2] + rq[3];
    const float mean = tot * (1.f / (float)CAT);
    const float var  = totq * (1.f / (float)CAT) - mean * mean;
    const float inv  = rsqrtf(var + EPS);

    float x1 = (v1 - mean) * inv + beta[t];
    x1 = (x1 > 0.f) ? x1 : ALPHA * x1;
    float d = x1 * Wf[t];
    if (t < N_KERNEL) {
        float x2 = (v2 - mean) * inv + beta[HID + t];
        x2 = (x2 > 0.f) ? x2 : ALPHA * x2;
        d += x2 * Wf[HID + t];
    }
#pragma unroll
    for (int off = 32; off > 0; off >>= 1) d += __shfl_down(d, off);
    if (lane == 0) rd[w] = d;
    __syncthreads();
    if (t == 0) out[row] = rd[0] + rd[1] + rd[2] + rd[3] + bf[0];
}

// ---------------------------------------------------------------------------
extern "C" void kernel_launch(void* const* d_in, const int* in_sizes, int n_in,
                              void* d_out, int out_size, void* d_ws, size_t ws_size,
                              hipStream_t stream)
{
    const float* x     = (const float*)d_in[0];
    const float* W0    = (const float*)d_in[1];
    const float* b0    = (const float*)d_in[2];
    const float* Wd0   = (const float*)d_in[3];
    const float* bd0   = (const float*)d_in[4];
    const float* beta0 = (const float*)d_in[5];
    const float* W1    = (const float*)d_in[6];
    const float* b1    = (const float*)d_in[7];
    const float* Wd1   = (const float*)d_in[8];
    const float* bd1   = (const float*)d_in[9];
    const float* beta1 = (const float*)d_in[10];
    const float* Wf    = (const float*)d_in[11];
    const float* bf    = (const float*)d_in[12];
    float* out = (float*)d_out;

    // ---- workspace layout: fp32 region, then bf16 (ushort) region ----
    float* fws = (float*)d_ws;
    float* h0     = fws;                        // 1024*256
    float* M0f    = h0   + 1024 * 256;          // 1024*128
    float* h1     = M0f  + 1024 * 128;          // 1024*256
    float* M1f    = h1   + 1024 * 256;          // 1024*128
    float* div0   = M1f  + 1024 * 128;          // 1024*10
    float* div1   = div0 + 1024 * 10;           // 1024*10
    float* bcomb0 = div1 + 1024 * 10;           // 128
    float* bcomb1 = bcomb0 + 128;               // 128
    unsigned short* uws = (unsigned short*)(bcomb1 + 128);
    unsigned short* xb    = uws;                 // 1024*512
    unsigned short* W0b   = xb    + 1024 * 512;  // 512*256
    unsigned short* W0bT  = W0b   + 512 * 256;   // 256*512
    unsigned short* Wd0bT = W0bT  + 256 * 512;   // 128*256
    unsigned short* W1b   = Wd0bT + 128 * 256;   // 288*256
    unsigned short* W1bT  = W1b   + 288 * 256;   // 256*288
    unsigned short* Wd1bT = W1bT  + 256 * 288;   // 128*256
    unsigned short* Wc0bT = Wd1bT + 128 * 256;   // 128*512
    unsigned short* Wc1bT = Wc0bT + 128 * 512;   // 128*288
    unsigned short* a0b   = Wc1bT + 128 * 288;   // 1024*288

    dim3 blk(256);

    // 1. convert/transpose/pad + bcomb
    conv_kernel<<<dim3(514), blk, 0, stream>>>(
        x, W0, Wd0, W1, Wd1, b0, bd0, b1, bd1,
        xb, W0b, W0bT, Wd0bT, W1b, W1bT, Wd1bT, bcomb0, bcomb1);

    // 2. Wc = (W @ Wd)^T, both blocks
    wc_mfma<<<dim3(100), blk, 0, stream>>>(Wd0bT, W0b, Wc0bT, Wd1bT, W1b, Wc1bT);

    // 3. stage 0: h0 = x@W0 + b0  ||  M0 = x@Wc0 + bcomb0
    hm_mfma<<<dim3(32, 12), blk, 0, stream>>>(
        xb, N_FEAT, W0bT, b0, h0, Wc0bT, bcomb0, M0f);

    // 4. diversity 0
    diversity_kernel<<<dim3(32, N_KERNEL), blk, 0, stream>>>(M0f, div0);

    // 5. LN0 -> a0 (bf16, padded to 288)
    ln_bf16_pad<<<dim3(N_ROWS), blk, 0, stream>>>(h0, div0, beta0, a0b);

    // 6. stage 1: h1 = a0@W1 + b1  ||  M1 = a0@Wc1 + bcomb1
    hm_mfma<<<dim3(32, 12), blk, 0, stream>>>(
        a0b, KPAD, W1bT, b1, h1, Wc1bT, bcomb1, M1f);

    // 7. diversity 1
    diversity_kernel<<<dim3(32, N_KERNEL), blk, 0, stream>>>(M1f, div1);

    // 8. LN1 + head
    ln_final<<<dim3(N_ROWS), blk, 0, stream>>>(h1, div1, beta1, Wf, bf, out);
}